// Round 7
// baseline (32.359 us; speedup 1.0000x reference)
//
#include <hip/hip_runtime.h>

#define NF       10000
#define NF_PAD   10240
#define PATCH    16
#define ENC      128
#define BB       8
#define HH       64
#define WW       32
#define NPOS     (BB*HH*WW)   // 16384

// f32 sum of 16, shuffle-halving tree order (CONFIRMED exact ref order for
// f_sum: R4/R6 show ~1 flip total vs ~100 for any deviating order).
__device__ __forceinline__ float tree_sum16(const float* a) {
    float b0 = a[0] + a[8],  b1 = a[1] + a[9],  b2 = a[2] + a[10], b3 = a[3] + a[11];
    float b4 = a[4] + a[12], b5 = a[5] + a[13], b6 = a[6] + a[14], b7 = a[7] + a[15];
    float c0 = b0 + b4, c1 = b1 + b5, c2 = b2 + b6, c3 = b3 + b7;
    float d0 = c0 + c2, d1 = c1 + c3;
    return d0 + d1;
}

// ---------------------------------------------------------------------------
// Kernel 1: f_sum[n] = tree_sum16(filters[n,:]); pad [NF, NF_PAD) with +inf.
// (BIT-IDENTICAL TO ROUNDS 4-6 — confirmed order.)
// ---------------------------------------------------------------------------
__global__ __launch_bounds__(256) void fsum_kernel(const float* __restrict__ filters,
                                                   float* __restrict__ fsum) {
    int n = blockIdx.x * blockDim.x + threadIdx.x;
    if (n >= NF_PAD) return;
    if (n >= NF) { fsum[n] = __builtin_inff(); return; }
    const float4* fp = reinterpret_cast<const float4*>(filters + n * PATCH);
    float4 v0 = fp[0], v1 = fp[1], v2 = fp[2], v3 = fp[3];
    float a[16] = {v0.x, v0.y, v0.z, v0.w, v1.x, v1.y, v1.z, v1.w,
                   v2.x, v2.y, v2.z, v2.w, v3.x, v3.y, v3.z, v3.w};
    fsum[n] = tree_sum16(a);
}

// ---------------------------------------------------------------------------
// Kernel 2: x_sum = tree_sum16 of  (v - mn) * (1.0f / rg)
// SINGLE CHANGE vs R4: reciprocal-multiply instead of per-element divide
// (LLVM -freciprocal-math hoists 1/rg for the loop-invariant divisor in the
// XLA:CPU fast-math ref). rinv = one correctly-rounded f32 divide.
// One block per (b,w): 64 threads = h. min/max exact.
// ---------------------------------------------------------------------------
__global__ __launch_bounds__(64) void xsum_kernel(const float* __restrict__ x,
                                                  float* __restrict__ xsum) {
    int bw = blockIdx.x;              // 0..255
    int b = bw >> 5, w = bw & 31;
    int h = threadIdx.x;              // 0..63
    const float4* xp = reinterpret_cast<const float4*>(
        x + (size_t)(((b * HH + h) * WW + w) * PATCH));
    float4 v0 = xp[0], v1 = xp[1], v2 = xp[2], v3 = xp[3];
    float v[16] = {v0.x, v0.y, v0.z, v0.w, v1.x, v1.y, v1.z, v1.w,
                   v2.x, v2.y, v2.z, v2.w, v3.x, v3.y, v3.z, v3.w};

    __shared__ float lds[64][17];
    __shared__ float smn[16], sinv[16];
    #pragma unroll
    for (int j = 0; j < 16; ++j) lds[h][j] = v[j];
    __syncthreads();
    if (h < 16) {
        float mn = lds[0][h], mx = mn;
        for (int i = 1; i < 64; ++i) {
            float t = lds[i][h];
            mn = fminf(mn, t);
            mx = fmaxf(mx, t);
        }
        smn[h] = mn;
        float rg = (mx - mn) + 1e-8f;   // f32, reference order
        sinv[h] = 1.0f / rg;            // one IEEE f32 divide (hoisted recip)
    }
    __syncthreads();

    float xs[16];
    #pragma unroll
    for (int j = 0; j < 16; ++j) xs[j] = (v[j] - smn[j]) * sinv[j];  // mul, not div
    xsum[(b * HH + h) * WW + w] = tree_sum16(xs);
}

// ---------------------------------------------------------------------------
// Kernel 3: per position, argmin_n fabsf(fsum[n] - s), first-index tie-break;
// then out[pos,:] = emb[idx,:]. One wave per position; fsum staged in LDS.
// Lane scans ascending n (strict < keeps first), lexicographic (val,idx)
// cross-lane reduce reproduces first-occurrence semantics exactly.
// (BIT-IDENTICAL TO ROUNDS 4-6.)
// ---------------------------------------------------------------------------
__global__ __launch_bounds__(512) void argmin_gather_kernel(
        const float* __restrict__ fsum, const float* __restrict__ xsum,
        const float* __restrict__ emb, float* __restrict__ out) {
    __shared__ __align__(16) float sf[NF_PAD];
    int tid = threadIdx.x;
    {
        float4* d = reinterpret_cast<float4*>(sf);
        const float4* g = reinterpret_cast<const float4*>(fsum);
        #pragma unroll
        for (int i = 0; i < NF_PAD / 4 / 512; ++i) d[tid + i * 512] = g[tid + i * 512];
    }
    __syncthreads();

    int lane = tid & 63;
    int wave = tid >> 6;
    int pos = blockIdx.x * 8 + wave;
    float s = xsum[pos];

    float bv = __builtin_inff();
    int bi = 0x7fffffff;
    #pragma unroll 4
    for (int k = 0; k < NF_PAD / 256; ++k) {
        int n = k * 256 + lane * 4;
        float4 f = *reinterpret_cast<const float4*>(sf + n);
        float a0 = fabsf(f.x - s);
        float a1 = fabsf(f.y - s);
        float a2 = fabsf(f.z - s);
        float a3 = fabsf(f.w - s);
        if (a0 < bv) { bv = a0; bi = n; }
        if (a1 < bv) { bv = a1; bi = n + 1; }
        if (a2 < bv) { bv = a2; bi = n + 2; }
        if (a3 < bv) { bv = a3; bi = n + 3; }
    }
    #pragma unroll
    for (int m = 1; m < 64; m <<= 1) {
        float ov = __shfl_xor(bv, m, 64);
        int oi = __shfl_xor(bi, m, 64);
        if (ov < bv || (ov == bv && oi < bi)) { bv = ov; bi = oi; }
    }

    const float2* er = reinterpret_cast<const float2*>(emb + (size_t)bi * ENC);
    float2*       op = reinterpret_cast<float2*>(out + (size_t)pos * ENC);
    op[lane] = er[lane];
}

// ---------------------------------------------------------------------------
extern "C" void kernel_launch(void* const* d_in, const int* in_sizes, int n_in,
                              void* d_out, int out_size, void* d_ws, size_t ws_size,
                              hipStream_t stream) {
    const float* x       = (const float*)d_in[0];  // (8,64,32,16)
    const float* filters = (const float*)d_in[1];  // (10000,16)
    const float* emb     = (const float*)d_in[2];  // (10000,128)
    float* out  = (float*)d_out;                   // (8,64,32,128)
    float* fsum = (float*)d_ws;                    // NF_PAD floats
    float* xsum = fsum + NF_PAD;                   // NPOS floats

    fsum_kernel<<<NF_PAD / 256, 256, 0, stream>>>(filters, fsum);
    xsum_kernel<<<BB * WW, 64, 0, stream>>>(x, xsum);
    argmin_gather_kernel<<<NPOS / 8, 512, 0, stream>>>(fsum, xsum, emb, out);
}